// Round 11
// baseline (72.117 us; speedup 1.0000x reference)
//
#include <hip/hip_runtime.h>

// Problem constants (fixed shapes from setup_inputs)
constexpr int NB = 8;     // batch
constexpr int ND = 1024;  // d = 32*32 cells
constexpr int NS = 500;   // noise samples n
constexpr int NK = 16;    // k
constexpr int NC = 3;     // channels
constexpr int NH = 1024;  // H
constexpr int NW = 1024;  // W
constexpr int NP = 64;    // patch size
constexpr int PTOP = 16;  // (p - sh)/2
constexpr int PLEFT = 16; // (p - sh)/2
constexpr float SIGMA = 0.05f;

// ---- Phase 1: normalize (blocks 0-7) + zero counts (all 64 blocks) ----
__global__ void normalize_kernel(const float* __restrict__ scores,
                                 float* __restrict__ s_norm,
                                 int* __restrict__ counts) {
    int blk = blockIdx.x;   // 64 blocks
    int t = threadIdx.x;

    int4 z4 = make_int4(0, 0, 0, 0);
    ((int4*)counts)[blk * 512 + t] = z4;
    ((int4*)counts)[blk * 512 + 256 + t] = z4;

    if (blk >= NB) return;
    int b = blk;
    float v[4];
#pragma unroll
    for (int q = 0; q < 4; q++) v[q] = scores[b * ND + t + 256 * q];
    float mn = fminf(fminf(v[0], v[1]), fminf(v[2], v[3]));
    float mx = fmaxf(fmaxf(v[0], v[1]), fmaxf(v[2], v[3]));
#pragma unroll
    for (int off = 1; off < 64; off <<= 1) {
        mn = fminf(mn, __shfl_xor(mn, off));
        mx = fmaxf(mx, __shfl_xor(mx, off));
    }
    __shared__ float smn[4], smx[4];
    int wave = t >> 6, lane = t & 63;
    if (lane == 0) { smn[wave] = mn; smx[wave] = mx; }
    __syncthreads();
    mn = fminf(fminf(smn[0], smn[1]), fminf(smn[2], smn[3]));
    mx = fmaxf(fmaxf(smx[0], smx[1]), fmaxf(smx[2], smx[3]));
    float den = mx - mn + 1e-5f;
#pragma unroll
    for (int q = 0; q < 4; q++)
        s_norm[b * ND + t + 256 * q] = (v[q] - mn) / den;
}

// ---------------- Phase 2: wave-per-sample top-16 -> integer histogram ----------------
__global__ void topk_kernel(const float* __restrict__ s_norm,
                            const float* __restrict__ noise,
                            int* __restrict__ counts) {
    int t = threadIdx.x;
    int wave = t >> 6, lane = t & 63;
    int sid = blockIdx.x * 4 + wave;          // 0 .. NB*NS-1 (grid is exact)
    int b = sid / NS;

    const float* sp = s_norm + b * ND;
    const float* npp = noise + (size_t)sid * ND;

    float v[16];
#pragma unroll
    for (int q = 0; q < 16; q++) {
        int j = q * 64 + lane;
        v[q] = sp[j] + npp[j] * SIGMA;
    }

    int myj = 0x7fffffff;
    for (int it = 0; it < NK; it++) {
        float bv = v[0];
        int bq = 0;
#pragma unroll
        for (int q = 1; q < 16; q++)
            if (v[q] > bv) { bv = v[q]; bq = q; }
        int bj = bq * 64 + lane;
#pragma unroll
        for (int off = 1; off < 64; off <<= 1) {
            float ov = __shfl_xor(bv, off);
            int oj = __shfl_xor(bj, off);
            if (ov > bv || (ov == bv && oj < bj)) { bv = ov; bj = oj; }
        }
        if (lane == it) myj = bj;
        int wq = bj >> 6, wl = bj & 63;
#pragma unroll
        for (int q = 0; q < 16; q++)
            v[q] = (q == wq && lane == wl) ? -1e30f : v[q];
    }

    int rank = 0;
#pragma unroll
    for (int u = 0; u < NK; u++) {
        int other = __shfl(myj, u);
        rank += (other < myj) ? 1 : 0;
    }
    if (lane < NK)
        atomicAdd(&counts[(b * NK + rank) * ND + myj], 1);
}

// ---------------- Phase 2.5: per-batch union of nonzero cells ----------------
// Block per b. Entry = cell index (i<<5|j); + 16 f32 weights (count/500).
__global__ void union_kernel(const int* __restrict__ counts,
                             int* __restrict__ ucell,
                             float* __restrict__ uw,
                             int* __restrict__ nunion) {
    int b = blockIdx.x;
    int t = threadIdx.x;
    int lane = t & 63, wave = t >> 6;
    const int* cp = counts + b * NK * ND;

    unsigned nz = 0;
    for (int kk = 0; kk < NK; kk++) {
        int4 c4 = *(const int4*)(cp + kk * ND + t * 4);
        if (c4.x) nz |= 1;
        if (c4.y) nz |= 2;
        if (c4.z) nz |= 4;
        if (c4.w) nz |= 8;
    }
    int cnt = __popc(nz);
    int incl = cnt;
#pragma unroll
    for (int off = 1; off < 64; off <<= 1) {
        int o = __shfl_up(incl, off);
        if (lane >= off) incl += o;
    }
    int excl = incl - cnt;
    __shared__ int wtot[4];
    if (lane == 63) wtot[wave] = incl;
    __syncthreads();
    int base = 0;
    for (int w = 0; w < wave; w++) base += wtot[w];
    int pos = base + excl;

    const float invn = 1.0f / (float)NS;
    int* up = ucell + b * ND;
    float* wp = uw + (size_t)b * ND * NK;
#pragma unroll
    for (int q = 0; q < 4; q++) {
        if (nz & (1u << q)) {
            int cell = t * 4 + q;
            up[pos] = cell;
            for (int kk = 0; kk < NK; kk++)
                wp[(size_t)pos * NK + kk] = (float)cp[kk * ND + cell] * invn;
            pos++;
        }
    }
    if (t == 0) nunion[b] = wtot[0] + wtot[1] + wtot[2] + wtot[3];
}

// ---------------- Phase 3: union gather — asm-load pipeline, counted vmcnt ----------------
// Grid 1536: blk = y*24 + bc (bc = b*3+c, XCD-pinned: 24%8==0). Block = one
// output row y, all 16 kk. 4 waves = entry slots (stride 4); LDS fixed-order
// cross-wave reduce at the end (deterministic, no atomics; out written once).
// Weights: staged once in LDS (broadcast ds_read_b128, lgkm counter — off the
// vmcnt path). x-loads: inline-asm global_load_dword in batches of 8, 2-deep
// pipeline, hand-counted s_waitcnt vmcnt(8) (never 0 mid-loop) + sched_barrier.
// This is the ONLY way to guarantee MLP>1: every C-level formulation since R3
// got per-value vmcnt(0) from the compiler (measured MLP~=1 across 7 variants).
constexpr int CAPE = 384;   // weights staged in LDS for e < CAPE (global beyond)

__global__ void __launch_bounds__(256)
gather_kernel(const int* __restrict__ ucell,
              const float* __restrict__ uw,
              const int* __restrict__ nunion,
              const float* __restrict__ x_high,
              float* __restrict__ out) {
    int blk = blockIdx.x;
    int bc = blk % 24;
    int y  = blk / 24;           // 0..63
    int b = bc / 3, c = bc % 3;
    int t = threadIdx.x;
    int w = t >> 6;              // wave = entry slot 0..3
    int x = t & 63;

    int U = nunion[b];
    int UC = U < CAPE ? U : CAPE;

    __shared__ int lc[ND];             // 4 KB
    __shared__ float4 lw4[CAPE * 4];   // 24 KB (reused as reduce buffer)

    const float* uwb = uw + (size_t)b * ND * NK;
    const float4* uw4 = (const float4*)uwb;
    for (int i = t; i < U; i += 256) lc[i] = ucell[b * ND + i];
    for (int i = t; i < UC * 4; i += 256) lw4[i] = uw4[i];
    __syncthreads();

    const float* xp = x_high + (size_t)bc * (NH * NW);
    int ym = y - PTOP;           // uniform per block
    int xm = x - PLEFT;          // per lane

    float acc[16];
#pragma unroll
    for (int q = 0; q < 16; q++) acc[q] = 0.f;

    int NBt = (U + 31) >> 5;     // batches of 8 entries (stride 4) per wave

    float xvA[8], xvB[8];
    unsigned okA = 0, okB = 0;

#define GISSUE(XV, OK, BI)                                                   \
    {                                                                        \
        OK = 0;                                                              \
        _Pragma("unroll")                                                    \
        for (int jj = 0; jj < 8; jj++) {                                     \
            int e = w + 4 * ((BI) * 8 + jj);                                 \
            int ee = (e < U) ? e : 0;                                        \
            int cell = lc[ee];                                               \
            int row = ((cell >> 5) << 5) + ym;                               \
            int col = ((cell & 31) << 5) + xm;                               \
            bool rok = (unsigned)row < 1024u;                                \
            bool cok = (unsigned)col < 1024u;                                \
            OK |= ((e < U) && rok && cok ? 1u : 0u) << jj;                   \
            int idx = (rok ? (row << 10) : 0) + (cok ? col : 0);             \
            const float* ga = xp + idx;                                      \
            asm volatile("global_load_dword %0, %1, off"                     \
                         : "=v"(XV[jj]) : "v"(ga));                          \
        }                                                                    \
    }

#define GCONSUME(XV, OK, BI)                                                 \
    {                                                                        \
        _Pragma("unroll")                                                    \
        for (int jj = 0; jj < 8; jj++) {                                     \
            int e = w + 4 * ((BI) * 8 + jj);                                 \
            if (e < U) {                                                     \
                float v = ((OK >> jj) & 1u) ? XV[jj] : 0.f;                  \
                float4 w0, w1, w2, w3;                                       \
                if (e < CAPE) {                                              \
                    w0 = lw4[e * 4 + 0]; w1 = lw4[e * 4 + 1];                \
                    w2 = lw4[e * 4 + 2]; w3 = lw4[e * 4 + 3];                \
                } else {                                                     \
                    w0 = uw4[e * 4 + 0]; w1 = uw4[e * 4 + 1];                \
                    w2 = uw4[e * 4 + 2]; w3 = uw4[e * 4 + 3];                \
                }                                                            \
                acc[0]  += w0.x * v; acc[1]  += w0.y * v;                    \
                acc[2]  += w0.z * v; acc[3]  += w0.w * v;                    \
                acc[4]  += w1.x * v; acc[5]  += w1.y * v;                    \
                acc[6]  += w1.z * v; acc[7]  += w1.w * v;                    \
                acc[8]  += w2.x * v; acc[9]  += w2.y * v;                    \
                acc[10] += w2.z * v; acc[11] += w2.w * v;                    \
                acc[12] += w3.x * v; acc[13] += w3.y * v;                    \
                acc[14] += w3.z * v; acc[15] += w3.w * v;                    \
            }                                                                \
        }                                                                    \
    }

    GISSUE(xvA, okA, 0);
    for (int bi = 0; bi < NBt; bi += 2) {
        bool haveB = (bi + 1) < NBt;
        if (haveB) {
            GISSUE(xvB, okB, bi + 1);
            asm volatile("s_waitcnt vmcnt(8)" ::: "memory");
        } else {
            asm volatile("s_waitcnt vmcnt(0)" ::: "memory");
        }
        __builtin_amdgcn_sched_barrier(0);
        GCONSUME(xvA, okA, bi);
        if (haveB) {
            bool haveA2 = (bi + 2) < NBt;
            if (haveA2) {
                GISSUE(xvA, okA, bi + 2);
                asm volatile("s_waitcnt vmcnt(8)" ::: "memory");
            } else {
                asm volatile("s_waitcnt vmcnt(0)" ::: "memory");
            }
            __builtin_amdgcn_sched_barrier(0);
            GCONSUME(xvB, okB, bi + 1);
        }
    }

    // fixed-order cross-wave reduce (reuse lw4 LDS; stride 17 -> conflict-free)
    __syncthreads();
    float* redf = (float*)lw4;
    if (w > 0) {
#pragma unroll
        for (int q = 0; q < 16; q++)
            redf[((w - 1) * 64 + x) * 17 + q] = acc[q];
    }
    __syncthreads();
    if (w == 0) {
#pragma unroll
        for (int q = 0; q < 16; q++) {
            float s = acc[q] + redf[(0 * 64 + x) * 17 + q]
                             + redf[(1 * 64 + x) * 17 + q]
                             + redf[(2 * 64 + x) * 17 + q];
            out[((size_t)(b * NK + q) * NC + c) * (NP * NP) + y * NP + x] = s;
        }
    }
}

extern "C" void kernel_launch(void* const* d_in, const int* in_sizes, int n_in,
                              void* d_out, int out_size, void* d_ws, size_t ws_size,
                              hipStream_t stream) {
    const float* scores = (const float*)d_in[0];
    const float* x_high = (const float*)d_in[1];
    const float* noise  = (const float*)d_in[2];

    char* ws = (char*)d_ws;
    float* s_norm = (float*)ws;                            // 32 KB
    int* counts   = (int*)(ws + 32 * 1024);                // 512 KB (int4-aligned)
    int* ucell    = (int*)(ws + 544 * 1024);               // 32 KB
    float* uw     = (float*)(ws + 576 * 1024);             // 512 KB
    int* nunion   = (int*)(ws + 1088 * 1024);              // 32 B

    normalize_kernel<<<64, 256, 0, stream>>>(scores, s_norm, counts);
    topk_kernel<<<NB * NS / 4, 256, 0, stream>>>(s_norm, noise, counts);
    union_kernel<<<NB, 256, 0, stream>>>(counts, ucell, uw, nunion);
    gather_kernel<<<24 * 64, 256, 0, stream>>>(ucell, uw, nunion, x_high,
                                               (float*)d_out);
}